// Round 1
// baseline (222.738 us; speedup 1.0000x reference)
//
#include <hip/hip_runtime.h>

// LearnPermutations: K=256 independent 256x256 log-domain Sinkhorn normalizations.
// One 1024-thread block per matrix; matrix register-resident (8x8 tile/thread).
// All math in log2 domain: exp/log are single v_exp_f32/v_log_f32.

#define KMAT 256

typedef unsigned uint2_ev __attribute__((ext_vector_type(2)));

__device__ __forceinline__ float fast_exp2(float x) {
#if __has_builtin(__builtin_amdgcn_exp2f)
  return __builtin_amdgcn_exp2f(x);
#else
  return exp2f(x);
#endif
}

__device__ __forceinline__ float fast_log2(float x) {
#if __has_builtin(__builtin_amdgcn_logf)
  return __builtin_amdgcn_logf(x);
#else
  return __log2f(x);
#endif
}

template <int CTRL>
__device__ __forceinline__ float dpp_movf(float x) {
  return __int_as_float(
      __builtin_amdgcn_update_dpp(0, __float_as_int(x), CTRL, 0xf, 0xf, true));
}

// Reduce over the aligned 32-lane half-group containing this lane.
// DPP row_ror within 16-lane rows, then permlane16_swap to join the two rows.
__device__ __forceinline__ float hgroup_max(float x) {
  x = fmaxf(x, dpp_movf<0x121>(x));  // row_ror:1
  x = fmaxf(x, dpp_movf<0x122>(x));  // row_ror:2
  x = fmaxf(x, dpp_movf<0x124>(x));  // row_ror:4
  x = fmaxf(x, dpp_movf<0x128>(x));  // row_ror:8
#if __has_builtin(__builtin_amdgcn_permlane16_swap)
  uint2_ev r = __builtin_amdgcn_permlane16_swap(
      (unsigned)__float_as_int(x), (unsigned)__float_as_int(x), false, false);
  return fmaxf(__int_as_float((int)r.x), __int_as_float((int)r.y));
#else
  return fmaxf(x, __shfl_xor(x, 16, 64));
#endif
}

__device__ __forceinline__ float hgroup_sum(float x) {
  x += dpp_movf<0x121>(x);
  x += dpp_movf<0x122>(x);
  x += dpp_movf<0x124>(x);
  x += dpp_movf<0x128>(x);
#if __has_builtin(__builtin_amdgcn_permlane16_swap)
  uint2_ev r = __builtin_amdgcn_permlane16_swap(
      (unsigned)__float_as_int(x), (unsigned)__float_as_int(x), false, false);
  return __int_as_float((int)r.x) + __int_as_float((int)r.y);
#else
  return x + __shfl_xor(x, 16, 64);
#endif
}

// Combine lane l with lane l^32 (commutative op) via permlane32_swap.
__device__ __forceinline__ float x32_max(float x) {
#if __has_builtin(__builtin_amdgcn_permlane32_swap)
  uint2_ev r = __builtin_amdgcn_permlane32_swap(
      (unsigned)__float_as_int(x), (unsigned)__float_as_int(x), false, false);
  return fmaxf(__int_as_float((int)r.x), __int_as_float((int)r.y));
#else
  return fmaxf(x, __shfl_xor(x, 32, 64));
#endif
}

__device__ __forceinline__ float x32_sum(float x) {
#if __has_builtin(__builtin_amdgcn_permlane32_swap)
  uint2_ev r = __builtin_amdgcn_permlane32_swap(
      (unsigned)__float_as_int(x), (unsigned)__float_as_int(x), false, false);
  return __int_as_float((int)r.x) + __int_as_float((int)r.y);
#else
  return x + __shfl_xor(x, 32, 64);
#endif
}

// Gumbel noise + temperature scaling, output in log2 domain.
// la_log2 = (plw - 0.01*ln(1e-20 - ln(u+1e-20))) * (log2e/tau)
__device__ __forceinline__ float gumbel_la(float p, float uv, float scale) {
  float lnu = fast_log2(uv + 1e-20f) * 0.69314718056f;          // ln(u+eps)
  float g = fast_log2(1e-20f - lnu) * (-0.0069314718056f);      // -0.01*ln(...)
  return (p + g) * scale;
}

__global__ __launch_bounds__(1024) void lp_sinkhorn_kernel(
    const float* __restrict__ plw, const float* __restrict__ uin,
    const int* __restrict__ itp, float* __restrict__ out) {
  const int k = blockIdx.x;
  const int t = threadIdx.x;
  const int br = t >> 5;   // 0..31 : block-row (8 rows each)
  const int bc = t & 31;   // 0..31 : block-col (8 cols each)
  const int wv = t >> 6;   // wave 0..15
  const int lane = t & 63;

  __shared__ float red[16 * 256];  // per-wave column partials (swizzled pos)
  __shared__ float colv[256];      // column max / column LSE (swizzled pos)

  // ---- schedule parameters from `iterations` (uniform) ----
  double frac = (double)itp[0] * 1e-5;  // iterations / 100000
  frac = frac < 0.0 ? 0.0 : (frac > 1.0 ? 1.0 : frac);
  const int n_iters = (int)(20.0 + frac * 130.0);
  // tau = 10^(-3 - 4*frac), rounded to fp32 like the reference
  const float tauf = (float)exp2((-3.0 - 4.0 * frac) * 3.3219280948873623);
  const float scale = (float)(1.4426950408889634 / (double)tauf);  // log2e/tau

  float la[8][8];

  // ---- load + gumbel + scale (8 rows x 2 float4 each) ----
  const float4* p4 = (const float4*)plw + k * 16384;
  const float4* u4 = (const float4*)uin + k * 16384;
#pragma unroll
  for (int i = 0; i < 8; ++i) {
    const int ridx = ((br << 3) + i) * 64 + (bc << 1);
    float4 p0 = p4[ridx];
    float4 p1 = p4[ridx + 1];
    float4 v0 = u4[ridx];
    float4 v1 = u4[ridx + 1];
    la[i][0] = gumbel_la(p0.x, v0.x, scale);
    la[i][1] = gumbel_la(p0.y, v0.y, scale);
    la[i][2] = gumbel_la(p0.z, v0.z, scale);
    la[i][3] = gumbel_la(p0.w, v0.w, scale);
    la[i][4] = gumbel_la(p1.x, v1.x, scale);
    la[i][5] = gumbel_la(p1.y, v1.y, scale);
    la[i][6] = gumbel_la(p1.z, v1.z, scale);
    la[i][7] = gumbel_la(p1.w, v1.w, scale);
  }

  // ---- Sinkhorn iterations ----
  for (int iter = 0; iter < n_iters; ++iter) {
    // ===== row normalize (axis=2): partners = 32 consecutive lanes =====
#pragma unroll
    for (int i = 0; i < 8; ++i) {
      float m = la[i][0];
#pragma unroll
      for (int j = 1; j < 8; ++j) m = fmaxf(m, la[i][j]);
      m = hgroup_max(m);
      float s = 0.f;
#pragma unroll
      for (int j = 0; j < 8; ++j) s += fast_exp2(la[i][j] - m);
      s = hgroup_sum(s);
      const float lse = m + fast_log2(s);
#pragma unroll
      for (int j = 0; j < 8; ++j) la[i][j] -= lse;
    }

    // ===== col normalize (axis=1) =====
    // local partial max over this thread's 8 rows, then wave (16 rows) via x32
    float cm[8];
#pragma unroll
    for (int j = 0; j < 8; ++j) {
      float m = la[0][j];
#pragma unroll
      for (int i = 1; i < 8; ++i) m = fmaxf(m, la[i][j]);
      cm[j] = x32_max(m);
    }
    // swizzled position pos = bc + 32*j for column c = 8*bc+j  (bank-conflict-free)
    if (lane < 32) {
#pragma unroll
      for (int j = 0; j < 8; ++j) red[wv * 256 + bc + 32 * j] = cm[j];
    }
    __syncthreads();

    float keepm = 0.f;
    if (t < 256) {
      float v[16];
#pragma unroll
      for (int w = 0; w < 16; ++w) v[w] = red[w * 256 + t];
#pragma unroll
      for (int s = 8; s >= 1; s >>= 1)
#pragma unroll
        for (int w = 0; w < s; ++w) v[w] = fmaxf(v[w], v[w + s]);
      keepm = v[0];
      colv[t] = v[0];
    }
    __syncthreads();

    // exp-sums against the global column max
#pragma unroll
    for (int j = 0; j < 8; ++j) {
      const float mj = colv[bc + 32 * j];
      float s = 0.f;
#pragma unroll
      for (int i = 0; i < 8; ++i) s += fast_exp2(la[i][j] - mj);
      cm[j] = x32_sum(s);
    }
    if (lane < 32) {
#pragma unroll
      for (int j = 0; j < 8; ++j) red[wv * 256 + bc + 32 * j] = cm[j];
    }
    __syncthreads();

    if (t < 256) {
      float v[16];
#pragma unroll
      for (int w = 0; w < 16; ++w) v[w] = red[w * 256 + t];
#pragma unroll
      for (int s = 8; s >= 1; s >>= 1)
#pragma unroll
        for (int w = 0; w < s; ++w) v[w] += v[w + s];
      colv[t] = keepm + fast_log2(v[0]);
    }
    __syncthreads();

#pragma unroll
    for (int j = 0; j < 8; ++j) {
      const float lse = colv[bc + 32 * j];
#pragma unroll
      for (int i = 0; i < 8; ++i) la[i][j] -= lse;
    }
    // next iteration's first __syncthreads (after red writes) protects colv reads
  }

  // ---- output: exp(log_alpha) = 2^la ----
  float4* o4 = (float4*)out + k * 16384;
#pragma unroll
  for (int i = 0; i < 8; ++i) {
    const int ridx = ((br << 3) + i) * 64 + (bc << 1);
    float4 a, b;
    a.x = fast_exp2(la[i][0]);
    a.y = fast_exp2(la[i][1]);
    a.z = fast_exp2(la[i][2]);
    a.w = fast_exp2(la[i][3]);
    b.x = fast_exp2(la[i][4]);
    b.y = fast_exp2(la[i][5]);
    b.z = fast_exp2(la[i][6]);
    b.w = fast_exp2(la[i][7]);
    o4[ridx] = a;
    o4[ridx + 1] = b;
  }
}

extern "C" void kernel_launch(void* const* d_in, const int* in_sizes, int n_in,
                              void* d_out, int out_size, void* d_ws,
                              size_t ws_size, hipStream_t stream) {
  const float* plw = (const float*)d_in[0];
  const float* u = (const float*)d_in[1];
  const int* iters = (const int*)d_in[2];
  float* out = (float*)d_out;
  (void)in_sizes; (void)n_in; (void)out_size; (void)d_ws; (void)ws_size;
  lp_sinkhorn_kernel<<<dim3(KMAT), dim3(1024), 0, stream>>>(plw, u, iters, out);
}

// Round 2
// 98.395 us; speedup vs baseline: 2.2637x; 2.2637x over previous
//
#include <hip/hip_runtime.h>

// LearnPermutations: K=256 independent 256x256 Sinkhorn normalizations.
// One 1024-thread block per matrix; matrix register-resident (8x8 tile/thread).
// Iteration 1 in log2 domain (handles huge dynamic range from tiny tau);
// iterations 2..n in LINEAR domain (provably safe: all sums in [1/256,256]),
// which eliminates ~128 transcendentals/thread/iter.

#define KMAT 256

typedef unsigned uint2_ev __attribute__((ext_vector_type(2)));

__device__ __forceinline__ float fast_exp2(float x) {
#if __has_builtin(__builtin_amdgcn_exp2f)
  return __builtin_amdgcn_exp2f(x);
#else
  return exp2f(x);
#endif
}

__device__ __forceinline__ float fast_log2(float x) {
#if __has_builtin(__builtin_amdgcn_logf)
  return __builtin_amdgcn_logf(x);
#else
  return __log2f(x);
#endif
}

__device__ __forceinline__ float fast_rcp(float x) {
#if __has_builtin(__builtin_amdgcn_rcpf)
  return __builtin_amdgcn_rcpf(x);
#else
  return 1.0f / x;
#endif
}

template <int CTRL>
__device__ __forceinline__ float dpp_movf(float x) {
  return __int_as_float(
      __builtin_amdgcn_update_dpp(0, __float_as_int(x), CTRL, 0xf, 0xf, true));
}

// Reduce over the aligned 32-lane half-group containing this lane.
__device__ __forceinline__ float hgroup_max(float x) {
  x = fmaxf(x, dpp_movf<0x121>(x));  // row_ror:1
  x = fmaxf(x, dpp_movf<0x122>(x));  // row_ror:2
  x = fmaxf(x, dpp_movf<0x124>(x));  // row_ror:4
  x = fmaxf(x, dpp_movf<0x128>(x));  // row_ror:8
#if __has_builtin(__builtin_amdgcn_permlane16_swap)
  uint2_ev r = __builtin_amdgcn_permlane16_swap(
      (unsigned)__float_as_int(x), (unsigned)__float_as_int(x), false, false);
  return fmaxf(__int_as_float((int)r.x), __int_as_float((int)r.y));
#else
  return fmaxf(x, __shfl_xor(x, 16, 64));
#endif
}

__device__ __forceinline__ float hgroup_sum(float x) {
  x += dpp_movf<0x121>(x);
  x += dpp_movf<0x122>(x);
  x += dpp_movf<0x124>(x);
  x += dpp_movf<0x128>(x);
#if __has_builtin(__builtin_amdgcn_permlane16_swap)
  uint2_ev r = __builtin_amdgcn_permlane16_swap(
      (unsigned)__float_as_int(x), (unsigned)__float_as_int(x), false, false);
  return __int_as_float((int)r.x) + __int_as_float((int)r.y);
#else
  return x + __shfl_xor(x, 16, 64);
#endif
}

__device__ __forceinline__ float x32_max(float x) {
#if __has_builtin(__builtin_amdgcn_permlane32_swap)
  uint2_ev r = __builtin_amdgcn_permlane32_swap(
      (unsigned)__float_as_int(x), (unsigned)__float_as_int(x), false, false);
  return fmaxf(__int_as_float((int)r.x), __int_as_float((int)r.y));
#else
  return fmaxf(x, __shfl_xor(x, 32, 64));
#endif
}

__device__ __forceinline__ float x32_sum(float x) {
#if __has_builtin(__builtin_amdgcn_permlane32_swap)
  uint2_ev r = __builtin_amdgcn_permlane32_swap(
      (unsigned)__float_as_int(x), (unsigned)__float_as_int(x), false, false);
  return __int_as_float((int)r.x) + __int_as_float((int)r.y);
#else
  return x + __shfl_xor(x, 32, 64);
#endif
}

// Gumbel noise + temperature scaling, output in log2 domain.
__device__ __forceinline__ float gumbel_la(float p, float uv, float scale) {
  float lnu = fast_log2(uv + 1e-20f) * 0.69314718056f;          // ln(u+eps)
  float g = fast_log2(1e-20f - lnu) * (-0.0069314718056f);      // -0.01*ln(...)
  return (p + g) * scale;
}

__global__ __launch_bounds__(1024, 1) void lp_sinkhorn_kernel(
    const float* __restrict__ plw, const float* __restrict__ uin,
    const int* __restrict__ itp, float* __restrict__ out) {
  const int k = blockIdx.x;
  const int t = threadIdx.x;
  const int br = t >> 5;   // 0..31 : block-row (8 rows each)
  const int bc = t & 31;   // 0..31 : block-col (8 cols each)
  const int wv = t >> 6;   // wave 0..15
  const int lane = t & 63;

  __shared__ float red[16 * 256];  // per-wave column partials (swizzled pos)
  __shared__ float colv[256];      // column max / LSE / rcp (swizzled pos)

  // ---- schedule parameters from `iterations` (uniform) ----
  double frac = (double)itp[0] * 1e-5;
  frac = frac < 0.0 ? 0.0 : (frac > 1.0 ? 1.0 : frac);
  const int n_iters = (int)(20.0 + frac * 130.0);
  const float tauf = (float)exp2((-3.0 - 4.0 * frac) * 3.3219280948873623);
  const float scale = (float)(1.4426950408889634 / (double)tauf);  // log2e/tau

  float la[8][8];

  // ---- load + gumbel + scale ----
  const float4* p4 = (const float4*)plw + k * 16384;
  const float4* u4 = (const float4*)uin + k * 16384;
#pragma unroll
  for (int i = 0; i < 8; ++i) {
    const int ridx = ((br << 3) + i) * 64 + (bc << 1);
    float4 p0 = p4[ridx];
    float4 p1 = p4[ridx + 1];
    float4 v0 = u4[ridx];
    float4 v1 = u4[ridx + 1];
    la[i][0] = gumbel_la(p0.x, v0.x, scale);
    la[i][1] = gumbel_la(p0.y, v0.y, scale);
    la[i][2] = gumbel_la(p0.z, v0.z, scale);
    la[i][3] = gumbel_la(p0.w, v0.w, scale);
    la[i][4] = gumbel_la(p1.x, v1.x, scale);
    la[i][5] = gumbel_la(p1.y, v1.y, scale);
    la[i][6] = gumbel_la(p1.z, v1.z, scale);
    la[i][7] = gumbel_la(p1.w, v1.w, scale);
  }

  // ======== iteration 1: LOG domain (row then col), ends in linear ========
  // row normalize (axis=2)
#pragma unroll
  for (int i = 0; i < 8; ++i) {
    float m = la[i][0];
#pragma unroll
    for (int j = 1; j < 8; ++j) m = fmaxf(m, la[i][j]);
    m = hgroup_max(m);
    float s = 0.f;
#pragma unroll
    for (int j = 0; j < 8; ++j) s += fast_exp2(la[i][j] - m);
    s = hgroup_sum(s);
    const float lse = m + fast_log2(s);
#pragma unroll
    for (int j = 0; j < 8; ++j) la[i][j] -= lse;
  }

  // col normalize (axis=1) in log domain; output converted to linear
  {
    float cm[8];
#pragma unroll
    for (int j = 0; j < 8; ++j) {
      float m = la[0][j];
#pragma unroll
      for (int i = 1; i < 8; ++i) m = fmaxf(m, la[i][j]);
      cm[j] = x32_max(m);
    }
    if (lane < 32) {
#pragma unroll
      for (int j = 0; j < 8; ++j) red[wv * 256 + bc + 32 * j] = cm[j];
    }
    __syncthreads();

    float keepm = 0.f;
    if (t < 256) {
      float v[16];
#pragma unroll
      for (int w = 0; w < 16; ++w) v[w] = red[w * 256 + t];
#pragma unroll
      for (int s = 8; s >= 1; s >>= 1)
#pragma unroll
        for (int w = 0; w < s; ++w) v[w] = fmaxf(v[w], v[w + s]);
      keepm = v[0];
      colv[t] = v[0];
    }
    __syncthreads();

#pragma unroll
    for (int j = 0; j < 8; ++j) {
      const float mj = colv[bc + 32 * j];
      float s = 0.f;
#pragma unroll
      for (int i = 0; i < 8; ++i) s += fast_exp2(la[i][j] - mj);
      cm[j] = x32_sum(s);
    }
    __syncthreads();   // protect colv before overwrite
    if (lane < 32) {
#pragma unroll
      for (int j = 0; j < 8; ++j) red[wv * 256 + bc + 32 * j] = cm[j];
    }
    __syncthreads();

    if (t < 256) {
      float v[16];
#pragma unroll
      for (int w = 0; w < 16; ++w) v[w] = red[w * 256 + t];
#pragma unroll
      for (int s = 8; s >= 1; s >>= 1)
#pragma unroll
        for (int w = 0; w < s; ++w) v[w] += v[w + s];
      colv[t] = keepm + fast_log2(v[0]);
    }
    __syncthreads();

    // convert to linear: p = exp2(la - col_lse)
#pragma unroll
    for (int j = 0; j < 8; ++j) {
      const float lse = colv[bc + 32 * j];
#pragma unroll
      for (int i = 0; i < 8; ++i) la[i][j] = fast_exp2(la[i][j] - lse);
    }
  }

  // ======== iterations 2..n: LINEAR domain ========
  // Invariant: entering each iteration, colsums == 1, so every row/col sum
  // encountered below is in [1/256, 256] -> rcp is safe and accurate.
  for (int iter = 1; iter < n_iters; ++iter) {
    // row normalize: in-wave only
#pragma unroll
    for (int i = 0; i < 8; ++i) {
      float s = la[i][0];
#pragma unroll
      for (int j = 1; j < 8; ++j) s += la[i][j];
      s = hgroup_sum(s);
      const float r = fast_rcp(s);
#pragma unroll
      for (int j = 0; j < 8; ++j) la[i][j] *= r;
    }

    // col partial sums
    float cs[8];
#pragma unroll
    for (int j = 0; j < 8; ++j) {
      float s = la[0][j];
#pragma unroll
      for (int i = 1; i < 8; ++i) s += la[i][j];
      cs[j] = x32_sum(s);
    }
    if (lane < 32) {
#pragma unroll
      for (int j = 0; j < 8; ++j) red[wv * 256 + bc + 32 * j] = cs[j];
    }
    __syncthreads();

    if (t < 256) {
      float v[16];
#pragma unroll
      for (int w = 0; w < 16; ++w) v[w] = red[w * 256 + t];
#pragma unroll
      for (int s = 8; s >= 1; s >>= 1)
#pragma unroll
        for (int w = 0; w < s; ++w) v[w] += v[w + s];
      colv[t] = fast_rcp(v[0]);
    }
    __syncthreads();

#pragma unroll
    for (int j = 0; j < 8; ++j) {
      const float c = colv[bc + 32 * j];
#pragma unroll
      for (int i = 0; i < 8; ++i) la[i][j] *= c;
    }
    // next iteration's post-write __syncthreads protects colv reads
  }

  // ---- output: already linear ----
  float4* o4 = (float4*)out + k * 16384;
#pragma unroll
  for (int i = 0; i < 8; ++i) {
    const int ridx = ((br << 3) + i) * 64 + (bc << 1);
    float4 a, b;
    a.x = la[i][0]; a.y = la[i][1]; a.z = la[i][2]; a.w = la[i][3];
    b.x = la[i][4]; b.y = la[i][5]; b.z = la[i][6]; b.w = la[i][7];
    o4[ridx] = a;
    o4[ridx + 1] = b;
  }
}

extern "C" void kernel_launch(void* const* d_in, const int* in_sizes, int n_in,
                              void* d_out, int out_size, void* d_ws,
                              size_t ws_size, hipStream_t stream) {
  const float* plw = (const float*)d_in[0];
  const float* u = (const float*)d_in[1];
  const int* iters = (const int*)d_in[2];
  float* out = (float*)d_out;
  (void)in_sizes; (void)n_in; (void)out_size; (void)d_ws; (void)ws_size;
  lp_sinkhorn_kernel<<<dim3(KMAT), dim3(1024), 0, stream>>>(plw, u, iters, out);
}

// Round 3
// 94.637 us; speedup vs baseline: 2.3536x; 1.0397x over previous
//
#include <hip/hip_runtime.h>

// LearnPermutations: K=256 independent 256x256 Sinkhorn normalizations.
// One 1024-thread block per matrix; matrix register-resident (8x8 tile/thread,
// stored as float2[8][4] to enable v_pk_* packed fp32).
// Iteration 1 in log2 domain (handles the huge 1/tau dynamic range), then
// scaling-vector Sinkhorn: u = rcp(A v), v = rcp(A^T u); matrix untouched
// until the final  out = a_ij * u_i * v_j.

#define KMAT 256

typedef unsigned uint2_ev __attribute__((ext_vector_type(2)));

__device__ __forceinline__ float fast_exp2(float x) {
#if __has_builtin(__builtin_amdgcn_exp2f)
  return __builtin_amdgcn_exp2f(x);
#else
  return exp2f(x);
#endif
}

__device__ __forceinline__ float fast_log2(float x) {
#if __has_builtin(__builtin_amdgcn_logf)
  return __builtin_amdgcn_logf(x);
#else
  return __log2f(x);
#endif
}

__device__ __forceinline__ float fast_rcp(float x) {
#if __has_builtin(__builtin_amdgcn_rcpf)
  return __builtin_amdgcn_rcpf(x);
#else
  return 1.0f / x;
#endif
}

__device__ __forceinline__ float2 pk_fma(float2 a, float2 b, float2 c) {
  return make_float2(fmaf(a.x, b.x, c.x), fmaf(a.y, b.y, c.y));
}
__device__ __forceinline__ float2 pk_mul(float2 a, float2 b) {
  return make_float2(a.x * b.x, a.y * b.y);
}
__device__ __forceinline__ float2 pk_sub1(float2 a, float s) {
  return make_float2(a.x - s, a.y - s);
}

template <int CTRL>
__device__ __forceinline__ float dpp_movf(float x) {
  return __int_as_float(
      __builtin_amdgcn_update_dpp(0, __float_as_int(x), CTRL, 0xf, 0xf, true));
}

// Reduce over the aligned 32-lane half-group containing this lane.
__device__ __forceinline__ float hgroup_max(float x) {
  x = fmaxf(x, dpp_movf<0x121>(x));  // row_ror:1
  x = fmaxf(x, dpp_movf<0x122>(x));  // row_ror:2
  x = fmaxf(x, dpp_movf<0x124>(x));  // row_ror:4
  x = fmaxf(x, dpp_movf<0x128>(x));  // row_ror:8
#if __has_builtin(__builtin_amdgcn_permlane16_swap)
  uint2_ev r = __builtin_amdgcn_permlane16_swap(
      (unsigned)__float_as_int(x), (unsigned)__float_as_int(x), false, false);
  return fmaxf(__int_as_float((int)r.x), __int_as_float((int)r.y));
#else
  return fmaxf(x, __shfl_xor(x, 16, 64));
#endif
}

__device__ __forceinline__ float hgroup_sum(float x) {
  x += dpp_movf<0x121>(x);
  x += dpp_movf<0x122>(x);
  x += dpp_movf<0x124>(x);
  x += dpp_movf<0x128>(x);
#if __has_builtin(__builtin_amdgcn_permlane16_swap)
  uint2_ev r = __builtin_amdgcn_permlane16_swap(
      (unsigned)__float_as_int(x), (unsigned)__float_as_int(x), false, false);
  return __int_as_float((int)r.x) + __int_as_float((int)r.y);
#else
  return x + __shfl_xor(x, 16, 64);
#endif
}

__device__ __forceinline__ float x32_max(float x) {
#if __has_builtin(__builtin_amdgcn_permlane32_swap)
  uint2_ev r = __builtin_amdgcn_permlane32_swap(
      (unsigned)__float_as_int(x), (unsigned)__float_as_int(x), false, false);
  return fmaxf(__int_as_float((int)r.x), __int_as_float((int)r.y));
#else
  return fmaxf(x, __shfl_xor(x, 32, 64));
#endif
}

__device__ __forceinline__ float x32_sum(float x) {
#if __has_builtin(__builtin_amdgcn_permlane32_swap)
  uint2_ev r = __builtin_amdgcn_permlane32_swap(
      (unsigned)__float_as_int(x), (unsigned)__float_as_int(x), false, false);
  return __int_as_float((int)r.x) + __int_as_float((int)r.y);
#else
  return x + __shfl_xor(x, 32, 64);
#endif
}

// Gumbel noise + temperature scaling, output in log2 domain.
__device__ __forceinline__ float gumbel_la(float p, float uv, float scale) {
  float lnu = fast_log2(uv + 1e-20f) * 0.69314718056f;          // ln(u+eps)
  float g = fast_log2(1e-20f - lnu) * (-0.0069314718056f);      // -0.01*ln(...)
  return (p + g) * scale;
}

__global__ __launch_bounds__(1024, 4) void lp_sinkhorn_kernel(
    const float* __restrict__ plw, const float* __restrict__ uin,
    const int* __restrict__ itp, float* __restrict__ out) {
  const int k = blockIdx.x;
  const int t = threadIdx.x;
  const int br = t >> 5;   // 0..31 : block-row (8 rows each)
  const int bc = t & 31;   // 0..31 : block-col (8 cols each)
  const int wv = t >> 6;   // wave 0..15
  const int lane = t & 63;

  __shared__ float red[16 * 256];  // per-wave column partials (swizzled pos)
  __shared__ float colv[256];      // column max / LSE / rcp (swizzled pos)

  // ---- schedule parameters from `iterations` (uniform) ----
  double frac = (double)itp[0] * 1e-5;
  frac = frac < 0.0 ? 0.0 : (frac > 1.0 ? 1.0 : frac);
  const int n_iters = (int)(20.0 + frac * 130.0);
  const float tauf = (float)exp2((-3.0 - 4.0 * frac) * 3.3219280948873623);
  const float scale = (float)(1.4426950408889634 / (double)tauf);  // log2e/tau

  // Thread's 8x8 tile: rows 8*br.., cols 8*bc.. ; col pair p covers cols
  // 8*bc+2p, 8*bc+2p+1.
  float2 la[8][4];

  // ---- load + gumbel + scale ----
  const float4* p4 = (const float4*)plw + k * 16384;
  const float4* u4 = (const float4*)uin + k * 16384;
#pragma unroll
  for (int i = 0; i < 8; ++i) {
    const int ridx = ((br << 3) + i) * 64 + (bc << 1);
    float4 p0 = p4[ridx];
    float4 p1 = p4[ridx + 1];
    float4 v0 = u4[ridx];
    float4 v1 = u4[ridx + 1];
    la[i][0] = make_float2(gumbel_la(p0.x, v0.x, scale),
                           gumbel_la(p0.y, v0.y, scale));
    la[i][1] = make_float2(gumbel_la(p0.z, v0.z, scale),
                           gumbel_la(p0.w, v0.w, scale));
    la[i][2] = make_float2(gumbel_la(p1.x, v1.x, scale),
                           gumbel_la(p1.y, v1.y, scale));
    la[i][3] = make_float2(gumbel_la(p1.z, v1.z, scale),
                           gumbel_la(p1.w, v1.w, scale));
  }

  // ======== iteration 1: LOG domain (row then col), ends linear ========
#pragma unroll
  for (int i = 0; i < 8; ++i) {
    float m = fmaxf(la[i][0].x, la[i][0].y);
#pragma unroll
    for (int p = 1; p < 4; ++p) m = fmaxf(m, fmaxf(la[i][p].x, la[i][p].y));
    m = hgroup_max(m);
    float s = 0.f;
#pragma unroll
    for (int p = 0; p < 4; ++p)
      s += fast_exp2(la[i][p].x - m) + fast_exp2(la[i][p].y - m);
    s = hgroup_sum(s);
    const float lse = m + fast_log2(s);
#pragma unroll
    for (int p = 0; p < 4; ++p) la[i][p] = pk_sub1(la[i][p], lse);
  }

  {  // col pass in log domain; convert to linear at the end
    float2 cm[4];
#pragma unroll
    for (int p = 0; p < 4; ++p) {
      float2 m = la[0][p];
#pragma unroll
      for (int i = 1; i < 8; ++i)
        m = make_float2(fmaxf(m.x, la[i][p].x), fmaxf(m.y, la[i][p].y));
      cm[p] = make_float2(x32_max(m.x), x32_max(m.y));
    }
    if (lane < 32) {
#pragma unroll
      for (int p = 0; p < 4; ++p) {
        red[wv * 256 + bc + 32 * (2 * p)] = cm[p].x;
        red[wv * 256 + bc + 32 * (2 * p + 1)] = cm[p].y;
      }
    }
    __syncthreads();

    float keepm = 0.f;
    if (t < 256) {
      float v[16];
#pragma unroll
      for (int w = 0; w < 16; ++w) v[w] = red[w * 256 + t];
#pragma unroll
      for (int s = 8; s >= 1; s >>= 1)
#pragma unroll
        for (int w = 0; w < s; ++w) v[w] = fmaxf(v[w], v[w + s]);
      keepm = v[0];
      colv[t] = v[0];
    }
    __syncthreads();

    float2 cs[4];
#pragma unroll
    for (int p = 0; p < 4; ++p) {
      const float2 mj = make_float2(colv[bc + 32 * (2 * p)],
                                    colv[bc + 32 * (2 * p + 1)]);
      float2 s = make_float2(0.f, 0.f);
#pragma unroll
      for (int i = 0; i < 8; ++i)
        s = make_float2(s.x + fast_exp2(la[i][p].x - mj.x),
                        s.y + fast_exp2(la[i][p].y - mj.y));
      cs[p] = make_float2(x32_sum(s.x), x32_sum(s.y));
    }
    __syncthreads();  // protect colv before overwrite
    if (lane < 32) {
#pragma unroll
      for (int p = 0; p < 4; ++p) {
        red[wv * 256 + bc + 32 * (2 * p)] = cs[p].x;
        red[wv * 256 + bc + 32 * (2 * p + 1)] = cs[p].y;
      }
    }
    __syncthreads();

    if (t < 256) {
      float v[16];
#pragma unroll
      for (int w = 0; w < 16; ++w) v[w] = red[w * 256 + t];
#pragma unroll
      for (int s = 8; s >= 1; s >>= 1)
#pragma unroll
        for (int w = 0; w < s; ++w) v[w] += v[w + s];
      colv[t] = keepm + fast_log2(v[0]);
    }
    __syncthreads();

    // convert to linear: a = exp2(la - col_lse); colsums(a) == 1
#pragma unroll
    for (int p = 0; p < 4; ++p) {
      const float2 lse = make_float2(colv[bc + 32 * (2 * p)],
                                     colv[bc + 32 * (2 * p + 1)]);
#pragma unroll
      for (int i = 0; i < 8; ++i)
        la[i][p] = make_float2(fast_exp2(la[i][p].x - lse.x),
                               fast_exp2(la[i][p].y - lse.y));
    }
  }

  // ======== iterations 2..n: scaling-vector Sinkhorn ========
  // u = rcp(A v); v = rcp(A^T u). Matrix registers are read-only here.
  // All sums in [1/256, 256] (colsums start at 1), so rcp is safe.
  float uo[8];
  float2 v2[4] = {make_float2(1.f, 1.f), make_float2(1.f, 1.f),
                  make_float2(1.f, 1.f), make_float2(1.f, 1.f)};

  for (int iter = 1; iter < n_iters; ++iter) {
    // row: u_i = rcp( sum_j a_ij * v_j )
#pragma unroll
    for (int i = 0; i < 8; ++i) {
      float2 acc = pk_mul(la[i][0], v2[0]);
#pragma unroll
      for (int p = 1; p < 4; ++p) acc = pk_fma(la[i][p], v2[p], acc);
      float s = hgroup_sum(acc.x + acc.y);
      uo[i] = fast_rcp(s);
    }

    // col partials: cs_j = sum_{i in my rows} a_ij * u_i
    float2 cs[4] = {make_float2(0.f, 0.f), make_float2(0.f, 0.f),
                    make_float2(0.f, 0.f), make_float2(0.f, 0.f)};
#pragma unroll
    for (int i = 0; i < 8; ++i) {
      const float2 ub = make_float2(uo[i], uo[i]);
#pragma unroll
      for (int p = 0; p < 4; ++p) cs[p] = pk_fma(la[i][p], ub, cs[p]);
    }
#pragma unroll
    for (int p = 0; p < 4; ++p)
      cs[p] = make_float2(x32_sum(cs[p].x), x32_sum(cs[p].y));

    if (lane < 32) {
#pragma unroll
      for (int p = 0; p < 4; ++p) {
        red[wv * 256 + bc + 32 * (2 * p)] = cs[p].x;
        red[wv * 256 + bc + 32 * (2 * p + 1)] = cs[p].y;
      }
    }
    __syncthreads();

    if (t < 256) {
      float v[16];
#pragma unroll
      for (int w = 0; w < 16; ++w) v[w] = red[w * 256 + t];
#pragma unroll
      for (int s = 8; s >= 1; s >>= 1)
#pragma unroll
        for (int w = 0; w < s; ++w) v[w] += v[w + s];
      colv[t] = fast_rcp(v[0]);
    }
    __syncthreads();

#pragma unroll
    for (int p = 0; p < 4; ++p)
      v2[p] = make_float2(colv[bc + 32 * (2 * p)],
                          colv[bc + 32 * (2 * p + 1)]);
    // next iteration's post-write __syncthreads protects colv/red hazards
  }

  // ---- output: out_ij = a_ij * u_i * v_j ----
  float4* o4 = (float4*)out + k * 16384;
#pragma unroll
  for (int i = 0; i < 8; ++i) {
    const int ridx = ((br << 3) + i) * 64 + (bc << 1);
    const float2 ub = make_float2(uo[i], uo[i]);
    float2 r0 = pk_mul(pk_mul(la[i][0], ub), v2[0]);
    float2 r1 = pk_mul(pk_mul(la[i][1], ub), v2[1]);
    float2 r2 = pk_mul(pk_mul(la[i][2], ub), v2[2]);
    float2 r3 = pk_mul(pk_mul(la[i][3], ub), v2[3]);
    float4 a, b;
    a.x = r0.x; a.y = r0.y; a.z = r1.x; a.w = r1.y;
    b.x = r2.x; b.y = r2.y; b.z = r3.x; b.w = r3.y;
    o4[ridx] = a;
    o4[ridx + 1] = b;
  }
}

extern "C" void kernel_launch(void* const* d_in, const int* in_sizes, int n_in,
                              void* d_out, int out_size, void* d_ws,
                              size_t ws_size, hipStream_t stream) {
  const float* plw = (const float*)d_in[0];
  const float* u = (const float*)d_in[1];
  const int* iters = (const int*)d_in[2];
  float* out = (float*)d_out;
  (void)in_sizes; (void)n_in; (void)out_size; (void)d_ws; (void)ws_size;
  lp_sinkhorn_kernel<<<dim3(KMAT), dim3(1024), 0, stream>>>(plw, u, iters, out);
}